// Round 8
// baseline (733.753 us; speedup 1.0000x reference)
//
#include <hip/hip_runtime.h>
#include <hip/hip_bf16.h>

// BinaryLinear: out = x @ sign(W)^T
// x: [32,4096,1024] f32 -> A [M=131072][K=1024]
// W: [1024,1024] f32    -> B^T = sign(W) [N=1024][K=1024] bf16 in d_ws (once)
// out: [M][N] f32
//
// R8 vs R6 (453us): R6's tallest pole is LDS (f32-A = 144KB/step -> 246us).
// Store A as bf16 (reg-stage + cvt_pk + padded ds_write) -> 96KB/step (187us
// pole). A(k+1) f32 loads are issued mid-step and waited at next entry
// vmcnt(0) (one compute phase + 2 barriers of cover -> latency hidden without
// R3's register cliff: only 16 f32/thread). B stays gll, packed 2-cols-per-
// 128B-row with XOR swizzle (restores R6's verified 8-slot conflict-free
// geometry at BK=32). Single-buffer A + 2 barriers/step = R6's race-free
// discipline; dbuf B target freed by barrier#0.

typedef __attribute__((ext_vector_type(8))) short bf16x8;
typedef __attribute__((ext_vector_type(4))) float f32x4;

#define BM 128
#define BN 128
#define BK 32
#define KDIM 1024
#define NDIM 1024
#define NKSTEP (KDIM / BK)
#define PADA 40  // ushorts per sA row: 32 data + 8 pad => 80-byte rows, conflict-free

__device__ __forceinline__ unsigned cvt2(float a, float b) {
  unsigned r;
  asm("v_cvt_pk_bf16_f32 %0, %1, %2" : "=v"(r) : "v"(a), "v"(b));
  return r;
}

// ---- pre-kernel: Bs[n][k] = sign(W[n][k]) as bf16 (+1, -1, or 0) ----
__global__ void sign_kernel(const float4* __restrict__ W, ushort4* __restrict__ Bs, int n4) {
  int i = blockIdx.x * blockDim.x + threadIdx.x;
  if (i >= n4) return;
  float4 v = W[i];
  const float* pv = (const float*)&v;
  ushort4 r;
  unsigned short* pr = (unsigned short*)&r;
#pragma unroll
  for (int j = 0; j < 4; ++j) {
    union { float f; unsigned int u; } c; c.f = pv[j];
    pr[j] = ((c.u & 0x7fffffffu) == 0u)
                ? (unsigned short)0
                : (unsigned short)(0x3f80u | ((c.u >> 16) & 0x8000u));
  }
  Bs[i] = r;
}

// ---- main GEMM ----
__global__ __launch_bounds__(256, 3) void bgemm_kernel(
    const float* __restrict__ X,
    const unsigned short* __restrict__ Bs,
    float* __restrict__ O) {
  __shared__ unsigned short sA[BM * PADA];   // 10240 B, single buffer (bf16, padded)
  __shared__ unsigned short sB[2][BN * BK];  // 2 x 8192 B (packed-pair layout)
  // total 26.6 KB -> LDS allows 6 blocks/CU; reg-capped ~3

  const int t = threadIdx.x;
  const int l = t & 63;
  const int w = t >> 6;
  const int wr = w >> 1;  // 2x2 wave grid, wave tile 64x64
  const int wc = w & 1;

  // XCD-bijective swizzle; bn fastest => 8 N-sharers of an M-tile on one XCD.
  const unsigned nwg = gridDim.x;
  unsigned swz = blockIdx.x;
  if ((nwg & 7u) == 0u) swz = (blockIdx.x & 7u) * (nwg >> 3) + (blockIdx.x >> 3);
  const int bm = (int)(swz >> 3);
  const int bn = (int)(swz & 7u);
  const size_t m0 = (size_t)bm * BM;
  const int N0 = bn * BN;

  // A staging: thread owns row r = t&127, k-half h = (t>>7)*16 (16 contiguous f32).
  const int ar = t & 127;
  const int ah = (t >> 7) * 16;
  const float* agl = X + (m0 + (size_t)ar) * KDIM + ah;
  const int awr = ar * PADA + ah;  // ushort index in sA

  // B staging (gll, dest linear): LDS chunk c (16B) packs 2 B-cols per 128B row:
  //   n = (c>>3)*2 + ((c&7)>>2), global k-octet q = (c&3) ^ ((c>>3)&3)
  const unsigned short* bgp[2];
  int bw[2];
#pragma unroll
  for (int i = 0; i < 2; ++i) {
    int c = i * 256 + t;
    int n = ((c >> 3) * 2) + ((c & 7) >> 2);
    int q = (c & 3) ^ ((c >> 3) & 3);
    bgp[i] = Bs + (size_t)(N0 + n) * KDIM + q * 8;
    bw[i] = c * 8;  // ushort index => byte offset c*16
  }

  // fragment read offsets
  const int ll = l & 15;
  const int kb = l >> 4;
  int offA[4];
#pragma unroll
  for (int i = 0; i < 4; ++i)
    offA[i] = (wr * 64 + i * 16 + ll) * PADA + kb * 8;
  int offB[4];
#pragma unroll
  for (int j = 0; j < 4; ++j) {
    int n = wc * 64 + j * 16 + ll;
    int s = (n & 1) * 4 + (kb ^ ((n >> 1) & 3));
    offB[j] = (n >> 1) * 64 + s * 8;
  }

  f32x4 acc[4][4];
#pragma unroll
  for (int i = 0; i < 4; ++i)
#pragma unroll
    for (int j = 0; j < 4; ++j) acc[i][j] = (f32x4)0.0f;

  float4 af0, af1, af2, af3;  // A(k+1) f32 prefetch (16 regs)

#define ISSUE(buf, k0)                                                         \
  do {                                                                         \
    _Pragma("unroll") for (int i = 0; i < 2; ++i)                              \
        __builtin_amdgcn_global_load_lds(                                      \
            (const __attribute__((address_space(1))) void*)(bgp[i] + (k0)),    \
            (__attribute__((address_space(3))) void*)(&sB[buf][bw[i]]),        \
            16, 0, 0);                                                         \
    const float4* ap = reinterpret_cast<const float4*>(agl + (k0));            \
    af0 = ap[0]; af1 = ap[1]; af2 = ap[2]; af3 = ap[3];                        \
  } while (0)

  // prologue: issue tile 0 (B -> sB[0] gll, A -> regs)
  ISSUE(0, 0);

#define STEP(CUR)                                                              \
  {                                                                            \
    asm volatile("s_waitcnt vmcnt(0)" ::: "memory");  /* A(k) regs, B(k) LDS */\
    uint4 lo, hi;                                                              \
    lo.x = cvt2(af0.x, af0.y); lo.y = cvt2(af0.z, af0.w);                      \
    lo.z = cvt2(af1.x, af1.y); lo.w = cvt2(af1.z, af1.w);                      \
    hi.x = cvt2(af2.x, af2.y); hi.y = cvt2(af2.z, af2.w);                      \
    hi.z = cvt2(af3.x, af3.y); hi.w = cvt2(af3.z, af3.w);                      \
    __syncthreads(); /* #0: all waves done reading sA(k-1) & sB[CUR^1](k-1) */ \
    *reinterpret_cast<uint4*>(&sA[awr]) = lo;                                  \
    *reinterpret_cast<uint4*>(&sA[awr + 8]) = hi;                              \
    if (kk + 1 < NKSTEP) ISSUE((CUR) ^ 1, (kk + 1) * BK);                      \
    asm volatile("s_waitcnt lgkmcnt(0)" ::: "memory"); /* A writes visible */  \
    __syncthreads(); /* #1 */                                                  \
    const unsigned short* sb = sB[CUR];                                        \
    bf16x8 av[4];                                                              \
    bf16x8 bv[4];                                                              \
    _Pragma("unroll") for (int i = 0; i < 4; ++i)                              \
        av[i] = *reinterpret_cast<const bf16x8*>(sA + offA[i]);                \
    _Pragma("unroll") for (int j = 0; j < 4; ++j)                              \
        bv[j] = *reinterpret_cast<const bf16x8*>(sb + offB[j]);                \
    _Pragma("unroll") for (int i = 0; i < 4; ++i)                              \
        _Pragma("unroll") for (int j = 0; j < 4; ++j)                          \
            acc[i][j] = __builtin_amdgcn_mfma_f32_16x16x32_bf16(               \
                av[i], bv[j], acc[i][j], 0, 0, 0);                             \
    ++kk;                                                                      \
  }

  int kk = 0;
  while (kk < NKSTEP) {
    STEP(0)
    STEP(1)
  }
#undef STEP
#undef ISSUE

  // epilogue: C/D layout col = lane&15, row = (lane>>4)*4 + reg
  const int crow = kb * 4;
#pragma unroll
  for (int i = 0; i < 4; ++i) {
    const size_t r0 = m0 + wr * 64 + i * 16 + crow;
#pragma unroll
    for (int j = 0; j < 4; ++j) {
      const int col = N0 + wc * 64 + j * 16 + ll;
      float* op = O + r0 * NDIM + col;
#pragma unroll
      for (int e = 0; e < 4; ++e) op[(size_t)e * NDIM] = acc[i][j][e];
    }
  }
}

// ---- fallback (only if ws too small for the 2 MiB sign buffer) ----
__global__ void naive_kernel(const float* __restrict__ X, const float* __restrict__ W,
                             float* __restrict__ O, long long total) {
  long long idx = (long long)blockIdx.x * blockDim.x + threadIdx.x;
  if (idx >= total) return;
  int n = (int)(idx & (NDIM - 1));
  long long m = idx >> 10;
  const float* xr = X + m * KDIM;
  const float* wr = W + (long long)n * KDIM;
  float s = 0.f;
  for (int k = 0; k < KDIM; ++k) {
    float wv = wr[k];
    float sg = (wv > 0.f) ? 1.f : ((wv < 0.f) ? -1.f : 0.f);
    s += xr[k] * sg;
  }
  O[idx] = s;
}

extern "C" void kernel_launch(void* const* d_in, const int* in_sizes, int n_in,
                              void* d_out, int out_size, void* d_ws, size_t ws_size,
                              hipStream_t stream) {
  const float* X = (const float*)d_in[0];
  const float* W = (const float*)d_in[1];
  float* O = (float*)d_out;
  const long long M = (long long)in_sizes[0] / KDIM;  // 131072

  const size_t need_ws = (size_t)NDIM * KDIM * sizeof(unsigned short);  // 2 MiB
  if (ws_size >= need_ws && (M % BM) == 0) {
    unsigned short* Bs = (unsigned short*)d_ws;
    int n4 = (NDIM * KDIM) / 4;
    sign_kernel<<<dim3(n4 / 256), dim3(256), 0, stream>>>(
        (const float4*)W, (ushort4*)Bs, n4);
    dim3 grid((unsigned)((M / BM) * (NDIM / BN)));  // 8192
    bgemm_kernel<<<grid, dim3(256), 0, stream>>>(X, Bs, O);
  } else {
    long long total = M * NDIM;
    long long blocks = (total + 255) / 256;
    naive_kernel<<<dim3((unsigned)blocks), dim3(256), 0, stream>>>(X, W, O, total);
  }
}

// Round 9
// 693.386 us; speedup vs baseline: 1.0582x; 1.0582x over previous
//
#include <hip/hip_runtime.h>
#include <hip/hip_bf16.h>

// BinaryLinear: out = x @ sign(W)^T
// x: [32,4096,1024] f32 -> A [M=131072][K=1024]
// W: [1024,1024] f32    -> B^T = sign(W) [N=1024][K=1024] bf16 in d_ws (once)
// out: [M][N] f32
//
// R9 = R6 (453us, race-free, 0 conflicts) with ONE change: A stored in LDS as
// BF16 instead of f32. Thread reg-loads 32 f32 (8x float4, coalesced), cvt_pk
// to bf16, 4x ds_write_b128 into a 144B-row padded tile -- all inside the same
// barriered stage phase; then R6's explicit vmcnt(0)+lgkmcnt(0) drain before
// the barrier (covers the B gll stream -> keeps conflicts at 0 and replay
// race-free). LDS traffic 144->96 KB/step (pole ~205us), LDS/block 48->34KB ->
// 4 blocks/CU (16 waves, launch_bounds(256,4) caps VGPR at 128).
// B path / fragment addressing / epilogue / XCD swizzle: R6 verbatim.

typedef __attribute__((ext_vector_type(8))) short bf16x8;
typedef __attribute__((ext_vector_type(4))) float f32x4;

#define BM 128
#define BN 128
#define BK 64
#define KDIM 1024
#define NDIM 1024
#define NKSTEP (KDIM / BK)
#define LDA 72  // ushorts per sA row: 64 data + 8 pad = 144-byte rows

__device__ __forceinline__ unsigned cvt2(float a, float b) {
  unsigned r;
  asm("v_cvt_pk_bf16_f32 %0, %1, %2" : "=v"(r) : "v"(a), "v"(b));
  return r;
}

// ---- pre-kernel: Bs[n][k] = sign(W[n][k]) as bf16 (+1, -1, or 0) ----
__global__ void sign_kernel(const float4* __restrict__ W, ushort4* __restrict__ Bs, int n4) {
  int i = blockIdx.x * blockDim.x + threadIdx.x;
  if (i >= n4) return;
  float4 v = W[i];
  const float* pv = (const float*)&v;
  ushort4 r;
  unsigned short* pr = (unsigned short*)&r;
#pragma unroll
  for (int j = 0; j < 4; ++j) {
    union { float f; unsigned int u; } c; c.f = pv[j];
    pr[j] = ((c.u & 0x7fffffffu) == 0u)
                ? (unsigned short)0
                : (unsigned short)(0x3f80u | ((c.u >> 16) & 0x8000u));
  }
  Bs[i] = r;
}

// ---- main GEMM ----
__global__ __launch_bounds__(256, 4) void bgemm_kernel(
    const float* __restrict__ X,
    const unsigned short* __restrict__ Bs,
    float* __restrict__ O) {
  __shared__ unsigned short sA[BM * LDA];  // 18 KB (bf16, padded rows)
  __shared__ unsigned short sB[BN * BK];   // 16 KB (XOR-slot layout, R6)
  // total ~34 KB -> 4 blocks/CU

  const int t = threadIdx.x;
  const int l = t & 63;
  const int w = t >> 6;
  const int wr = w >> 1;  // 2x2 wave grid, wave tile 64x64
  const int wc = w & 1;

  // XCD-bijective swizzle; bn fastest => 8 N-sharers of an M-tile on one XCD.
  const unsigned nwg = gridDim.x;
  unsigned swz = blockIdx.x;
  if ((nwg & 7u) == 0u) swz = (blockIdx.x & 7u) * (nwg >> 3) + (blockIdx.x >> 3);
  const int bm = (int)(swz >> 3);
  const int bn = (int)(swz & 7u);
  const size_t m0 = (size_t)bm * BM;
  const int N0 = bn * BN;

  // A staging: thread owns row r = t>>1, half h = t&1 -> 32 contiguous f32.
  const int ar = t >> 1;
  const int ah = t & 1;
  const float* agl = X + (m0 + (size_t)ar) * KDIM + ah * 32;
  const int awo = ar * LDA + ah * 32;  // ushort offset in sA

  // B staging: 128x64 bf16 = 1024 16B-chunks, 4 gll/thread (R6 verbatim).
  // LDS chunk c = n*8 + s holds global k-octet q = s ^ (n&7).
  const unsigned short* bgp[4];
  int bw[4];
#pragma unroll
  for (int i = 0; i < 4; ++i) {
    int c = i * 256 + t;
    int n = c >> 3;
    int q = (c & 7) ^ (n & 7);
    bgp[i] = Bs + (size_t)(N0 + n) * KDIM + q * 8;
    bw[i] = c * 8;  // linear dest (gll rule)
  }

  // fragment read offsets (2 k-subs of 32 per BK=64 step)
  const int ll = l & 15;
  const int kb = l >> 4;
  int offA[2][4];
  int offB[2][4];
#pragma unroll
  for (int ks = 0; ks < 2; ++ks) {
#pragma unroll
    for (int i = 0; i < 4; ++i) {
      int row = wr * 64 + i * 16 + ll;
      offA[ks][i] = row * LDA + ks * 32 + kb * 8;
    }
#pragma unroll
    for (int j = 0; j < 4; ++j) {
      int n = wc * 64 + j * 16 + ll;
      offB[ks][j] = n * 64 + (((ks * 4 + kb) ^ (n & 7)) * 8);
    }
  }

  f32x4 acc[4][4];
#pragma unroll
  for (int i = 0; i < 4; ++i)
#pragma unroll
    for (int j = 0; j < 4; ++j) acc[i][j] = (f32x4)0.0f;

  for (int kk = 0; kk < NKSTEP; ++kk) {
    const int k0 = kk * BK;

    // ---- stage phase ----
    // A f32 -> regs (issued first so the cvt wait doesn't wait on B)
    const float4* ap = reinterpret_cast<const float4*>(agl + k0);
    float4 f0 = ap[0], f1 = ap[1], f2 = ap[2], f3 = ap[3];
    float4 f4 = ap[4], f5 = ap[5], f6 = ap[6], f7 = ap[7];
    // B -> LDS via gll (in flight while we convert A)
#pragma unroll
    for (int i = 0; i < 4; ++i)
      __builtin_amdgcn_global_load_lds(
          (const __attribute__((address_space(1))) void*)(bgp[i] + k0),
          (__attribute__((address_space(3))) void*)(&sB[bw[i]]), 16, 0, 0);
    // cvt + padded ds_write (waits A loads as values arrive)
    uint4 q0, q1, q2, q3;
    q0.x = cvt2(f0.x, f0.y); q0.y = cvt2(f0.z, f0.w);
    q0.z = cvt2(f1.x, f1.y); q0.w = cvt2(f1.z, f1.w);
    q1.x = cvt2(f2.x, f2.y); q1.y = cvt2(f2.z, f2.w);
    q1.z = cvt2(f3.x, f3.y); q1.w = cvt2(f3.z, f3.w);
    q2.x = cvt2(f4.x, f4.y); q2.y = cvt2(f4.z, f4.w);
    q2.z = cvt2(f5.x, f5.y); q2.w = cvt2(f5.z, f5.w);
    q3.x = cvt2(f6.x, f6.y); q3.y = cvt2(f6.z, f6.w);
    q3.z = cvt2(f7.x, f7.y); q3.w = cvt2(f7.z, f7.w);
    *reinterpret_cast<uint4*>(&sA[awo]) = q0;
    *reinterpret_cast<uint4*>(&sA[awo + 8]) = q1;
    *reinterpret_cast<uint4*>(&sA[awo + 16]) = q2;
    *reinterpret_cast<uint4*>(&sA[awo + 24]) = q3;
    // drain: B gll data in LDS + A ds_writes visible before anyone crosses
    asm volatile("s_waitcnt vmcnt(0) lgkmcnt(0)" ::: "memory");
    __syncthreads();

    // ---- compute: 2 k-subs x 16 MFMA ----
#pragma unroll
    for (int ks = 0; ks < 2; ++ks) {
      bf16x8 av[4];
      bf16x8 bv[4];
#pragma unroll
      for (int i = 0; i < 4; ++i)
        av[i] = *reinterpret_cast<const bf16x8*>(sA + offA[ks][i]);
#pragma unroll
      for (int j = 0; j < 4; ++j)
        bv[j] = *reinterpret_cast<const bf16x8*>(sB + offB[ks][j]);
#pragma unroll
      for (int i = 0; i < 4; ++i)
#pragma unroll
        for (int j = 0; j < 4; ++j)
          acc[i][j] = __builtin_amdgcn_mfma_f32_16x16x32_bf16(
              av[i], bv[j], acc[i][j], 0, 0, 0);
    }
    __syncthreads();  // all reads done before next step's stage overwrites
  }

  // epilogue: C/D layout col = lane&15, row = (lane>>4)*4 + reg
  const int crow = kb * 4;
#pragma unroll
  for (int i = 0; i < 4; ++i) {
    const size_t r0 = m0 + wr * 64 + i * 16 + crow;
#pragma unroll
    for (int j = 0; j < 4; ++j) {
      const int col = N0 + wc * 64 + j * 16 + ll;
      float* op = O + r0 * NDIM + col;
#pragma unroll
      for (int e = 0; e < 4; ++e) op[(size_t)e * NDIM] = acc[i][j][e];
    }
  }
}

// ---- fallback (only if ws too small for the 2 MiB sign buffer) ----
__global__ void naive_kernel(const float* __restrict__ X, const float* __restrict__ W,
                             float* __restrict__ O, long long total) {
  long long idx = (long long)blockIdx.x * blockDim.x + threadIdx.x;
  if (idx >= total) return;
  int n = (int)(idx & (NDIM - 1));
  long long m = idx >> 10;
  const float* xr = X + m * KDIM;
  const float* wr = W + (long long)n * KDIM;
  float s = 0.f;
  for (int k = 0; k < KDIM; ++k) {
    float wv = wr[k];
    float sg = (wv > 0.f) ? 1.f : ((wv < 0.f) ? -1.f : 0.f);
    s += xr[k] * sg;
  }
  O[idx] = s;
}

extern "C" void kernel_launch(void* const* d_in, const int* in_sizes, int n_in,
                              void* d_out, int out_size, void* d_ws, size_t ws_size,
                              hipStream_t stream) {
  const float* X = (const float*)d_in[0];
  const float* W = (const float*)d_in[1];
  float* O = (float*)d_out;
  const long long M = (long long)in_sizes[0] / KDIM;  // 131072

  const size_t need_ws = (size_t)NDIM * KDIM * sizeof(unsigned short);  // 2 MiB
  if (ws_size >= need_ws && (M % BM) == 0) {
    unsigned short* Bs = (unsigned short*)d_ws;
    int n4 = (NDIM * KDIM) / 4;
    sign_kernel<<<dim3(n4 / 256), dim3(256), 0, stream>>>(
        (const float4*)W, (ushort4*)Bs, n4);
    dim3 grid((unsigned)((M / BM) * (NDIM / BN)));  // 8192
    bgemm_kernel<<<grid, dim3(256), 0, stream>>>(X, Bs, O);
  } else {
    long long total = M * NDIM;
    long long blocks = (total + 255) / 256;
    naive_kernel<<<dim3((unsigned)blocks), dim3(256), 0, stream>>>(X, W, O, total);
  }
}

// Round 10
// 513.808 us; speedup vs baseline: 1.4281x; 1.3495x over previous
//
#include <hip/hip_runtime.h>
#include <hip/hip_bf16.h>

// BinaryLinear: out = x @ sign(W)^T
// x: [32,4096,1024] f32 -> A [M=131072][K=1024]
// W: [1024,1024] f32    -> B^T = sign(W) [N=1024][K=1024] bf16 in d_ws (once)
// out: [M][N] f32
//
// R10 = R7's dbuf geometry (BK=32, 48KB, 3 blk/CU, all-gll staging) with the
// T4 counted-vmcnt discipline:
//   step kk: STAGE(buf^1, kk+1)   (6 gll)
//            s_waitcnt vmcnt(6)   (waits for LAST step's stage only -- the
//                                  prefetch issued this step stays in flight)
//            barrier; compute(buf); barrier
// vs R7 which drained vmcnt(0) at END of each step (exposed remainder latency
// every step -> 590us). vs R6 (453us) which serialized stage->drain->compute.
// Race audit: stage of buf X at step kk is after step kk-1's trailing barrier
// (which follows all reads of X); per-wave counted wait + barrier makes the
// collective staging visible. Tail step uses vmcnt(0).

typedef __attribute__((ext_vector_type(8))) short bf16x8;
typedef __attribute__((ext_vector_type(4))) float f32x4;

#define BM 128
#define BN 128
#define BK 32
#define KDIM 1024
#define NDIM 1024
#define NKSTEP (KDIM / BK)

__device__ __forceinline__ unsigned cvt2(float a, float b) {
  unsigned r;
  asm("v_cvt_pk_bf16_f32 %0, %1, %2" : "=v"(r) : "v"(a), "v"(b));
  return r;
}

// ---- pre-kernel: Bs[n][k] = sign(W[n][k]) as bf16 (+1, -1, or 0) ----
__global__ void sign_kernel(const float4* __restrict__ W, ushort4* __restrict__ Bs, int n4) {
  int i = blockIdx.x * blockDim.x + threadIdx.x;
  if (i >= n4) return;
  float4 v = W[i];
  const float* pv = (const float*)&v;
  ushort4 r;
  unsigned short* pr = (unsigned short*)&r;
#pragma unroll
  for (int j = 0; j < 4; ++j) {
    union { float f; unsigned int u; } c; c.f = pv[j];
    pr[j] = ((c.u & 0x7fffffffu) == 0u)
                ? (unsigned short)0
                : (unsigned short)(0x3f80u | ((c.u >> 16) & 0x8000u));
  }
  Bs[i] = r;
}

// ---- main GEMM ----
__global__ __launch_bounds__(256, 3) void bgemm_kernel(
    const float* __restrict__ X,
    const unsigned short* __restrict__ Bs,
    float* __restrict__ O) {
  // per buffer: A 128x8 f32x4 chunks (16KB) + B 128x32 bf16 (8KB) = 24KB; x2 = 48KB
  __shared__ f32x4 sA[2][BM * 8];
  __shared__ unsigned short sB[2][BN * BK];

  const int t = threadIdx.x;
  const int l = t & 63;
  const int w = t >> 6;
  const int wr = w >> 1;  // 2x2 wave grid, wave tile 64x64
  const int wc = w & 1;

  // XCD-bijective swizzle; bn fastest => 8 N-sharers of an M-tile on one XCD.
  const unsigned nwg = gridDim.x;
  unsigned swz = blockIdx.x;
  if ((nwg & 7u) == 0u) swz = (blockIdx.x & 7u) * (nwg >> 3) + (blockIdx.x >> 3);
  const int bm = (int)(swz >> 3);
  const int bn = (int)(swz & 7u);
  const size_t m0 = (size_t)bm * BM;
  const int N0 = bn * BN;

  // A staging: 128x32 f32 = 1024 16B-chunks, 4 gll/thread.
  // LDS chunk c = r*8 + s holds global k-chunk q = s ^ (r&7)  (both-sides XOR).
  const float* agp[4];
#pragma unroll
  for (int i = 0; i < 4; ++i) {
    int c = i * 256 + t;
    int r = c >> 3;
    int q = (c & 7) ^ (r & 7);
    agp[i] = X + (m0 + (size_t)r) * KDIM + q * 4;
  }

  // B staging: 128x32 bf16 = 512 16B-chunks, 2 gll/thread.
  // LDS chunk c = n*4 + s holds global k-octet q = s ^ ((n>>1)&3).
  const unsigned short* bgp[2];
#pragma unroll
  for (int i = 0; i < 2; ++i) {
    int c = i * 256 + t;
    int n = c >> 2;
    int q = (c & 3) ^ ((n >> 1) & 3);
    bgp[i] = Bs + (size_t)(N0 + n) * KDIM + q * 8;
  }

  // fragment read offsets
  const int ll = l & 15;
  const int kb = l >> 4;
  int idxA[4];  // f32x4-chunk index of low half of k-octet; high = ^1
#pragma unroll
  for (int i = 0; i < 4; ++i) {
    int row = wr * 64 + i * 16 + ll;
    idxA[i] = row * 8 + ((kb * 2) ^ (row & 7));
  }
  int offB[4];
#pragma unroll
  for (int j = 0; j < 4; ++j) {
    int n = wc * 64 + j * 16 + ll;
    int q = kb ^ ((n >> 1) & 3);
    offB[j] = n * BK + q * 8;
  }

  f32x4 acc[4][4];
#pragma unroll
  for (int i = 0; i < 4; ++i)
#pragma unroll
    for (int j = 0; j < 4; ++j) acc[i][j] = (f32x4)0.0f;

#define STAGE(buf, k0)                                                         \
  do {                                                                         \
    _Pragma("unroll") for (int i = 0; i < 4; ++i)                              \
        __builtin_amdgcn_global_load_lds(                                      \
            (const __attribute__((address_space(1))) void*)(agp[i] + (k0)),    \
            (__attribute__((address_space(3))) void*)(&sA[buf][i * 256 + t]),  \
            16, 0, 0);                                                         \
    _Pragma("unroll") for (int i = 0; i < 2; ++i)                              \
        __builtin_amdgcn_global_load_lds(                                      \
            (const __attribute__((address_space(1))) void*)(bgp[i] + (k0)),    \
            (__attribute__((address_space(3))) void*)(&sB[buf][(i * 256 + t) * 8]), \
            16, 0, 0);                                                         \
  } while (0)

  // prologue: issue stage of tile 0 (no wait here; step 0's counted wait covers it)
  STAGE(0, 0);

#define STEP(CUR)                                                              \
  {                                                                            \
    if (kk + 1 < NKSTEP) {                                                     \
      STAGE((CUR) ^ 1, (kk + 1) * BK);                                         \
      asm volatile("s_waitcnt vmcnt(6)" ::: "memory");                         \
    } else {                                                                   \
      asm volatile("s_waitcnt vmcnt(0)" ::: "memory");                         \
    }                                                                          \
    __syncthreads(); /* buf(kk) staged by ALL waves -> readable */             \
    const unsigned short* sb = sB[CUR];                                        \
    bf16x8 bv[4];                                                              \
    _Pragma("unroll") for (int j = 0; j < 4; ++j)                              \
        bv[j] = *reinterpret_cast<const bf16x8*>(sb + offB[j]);                \
    bf16x8 av[4];                                                              \
    _Pragma("unroll") for (int i = 0; i < 4; ++i) {                            \
      f32x4 c0 = sA[CUR][idxA[i]];                                             \
      f32x4 c1 = sA[CUR][idxA[i] ^ 1];                                         \
      union { uint4 u; bf16x8 v; } cv;                                         \
      cv.u.x = cvt2(c0.x, c0.y); cv.u.y = cvt2(c0.z, c0.w);                    \
      cv.u.z = cvt2(c1.x, c1.y); cv.u.w = cvt2(c1.z, c1.w);                    \
      av[i] = cv.v;                                                            \
    }                                                                          \
    _Pragma("unroll") for (int i = 0; i < 4; ++i)                              \
        _Pragma("unroll") for (int j = 0; j < 4; ++j)                          \
            acc[i][j] = __builtin_amdgcn_mfma_f32_16x16x32_bf16(               \
                av[i], bv[j], acc[i][j], 0, 0, 0);                             \
    __syncthreads(); /* reads of buf(kk) done before step kk+1 restages it */  \
    ++kk;                                                                      \
  }

  int kk = 0;
  while (kk < NKSTEP) {
    STEP(0)
    STEP(1)
  }
#undef STEP
#undef STAGE

  // epilogue: C/D layout col = lane&15, row = (lane>>4)*4 + reg
  const int crow = kb * 4;
#pragma unroll
  for (int i = 0; i < 4; ++i) {
    const size_t r0 = m0 + wr * 64 + i * 16 + crow;
#pragma unroll
    for (int j = 0; j < 4; ++j) {
      const int col = N0 + wc * 64 + j * 16 + ll;
      float* op = O + r0 * NDIM + col;
#pragma unroll
      for (int e = 0; e < 4; ++e) op[(size_t)e * NDIM] = acc[i][j][e];
    }
  }
}

// ---- fallback (only if ws too small for the 2 MiB sign buffer) ----
__global__ void naive_kernel(const float* __restrict__ X, const float* __restrict__ W,
                             float* __restrict__ O, long long total) {
  long long idx = (long long)blockIdx.x * blockDim.x + threadIdx.x;
  if (idx >= total) return;
  int n = (int)(idx & (NDIM - 1));
  long long m = idx >> 10;
  const float* xr = X + m * KDIM;
  const float* wr = W + (long long)n * KDIM;
  float s = 0.f;
  for (int k = 0; k < KDIM; ++k) {
    float wv = wr[k];
    float sg = (wv > 0.f) ? 1.f : ((wv < 0.f) ? -1.f : 0.f);
    s += xr[k] * sg;
  }
  O[idx] = s;
}

extern "C" void kernel_launch(void* const* d_in, const int* in_sizes, int n_in,
                              void* d_out, int out_size, void* d_ws, size_t ws_size,
                              hipStream_t stream) {
  const float* X = (const float*)d_in[0];
  const float* W = (const float*)d_in[1];
  float* O = (float*)d_out;
  const long long M = (long long)in_sizes[0] / KDIM;  // 131072

  const size_t need_ws = (size_t)NDIM * KDIM * sizeof(unsigned short);  // 2 MiB
  if (ws_size >= need_ws && (M % BM) == 0) {
    unsigned short* Bs = (unsigned short*)d_ws;
    int n4 = (NDIM * KDIM) / 4;
    sign_kernel<<<dim3(n4 / 256), dim3(256), 0, stream>>>(
        (const float4*)W, (ushort4*)Bs, n4);
    dim3 grid((unsigned)((M / BM) * (NDIM / BN)));  // 8192
    bgemm_kernel<<<grid, dim3(256), 0, stream>>>(X, Bs, O);
  } else {
    long long total = M * NDIM;
    long long blocks = (total + 255) / 256;
    naive_kernel<<<dim3((unsigned)blocks), dim3(256), 0, stream>>>(X, W, O, total);
  }
}